// Round 1
// baseline (778.339 us; speedup 1.0000x reference)
//
#include <hip/hip_runtime.h>
#include <stdint.h>

#define N_TOK 4096
#define CDIM  2048
#define NEXP  8
#define IDIM  1408
#define ISDIM 2816
#define CAP   2048

typedef __attribute__((ext_vector_type(8))) short bf16x8;
typedef __attribute__((ext_vector_type(4))) float f32x4;

#define GLOAD16(gp, lp) __builtin_amdgcn_global_load_lds( \
    (const __attribute__((address_space(1))) void*)(gp),  \
    (__attribute__((address_space(3))) void*)(lp), 16, 0, 0)

__device__ __forceinline__ unsigned short f2bf(float f) {
  union { float f; unsigned u; } c; c.f = f;
  return (unsigned short)((c.u + 0x7FFFu + ((c.u >> 16) & 1u)) >> 16);
}
__device__ __forceinline__ float bf2f(unsigned short h) {
  union { unsigned u; float f; } c; c.u = (unsigned)h << 16;
  return c.f;
}

// ---------------- fp32 -> bf16 convert ----------------
__global__ __launch_bounds__(256) void cvt_kernel(
    const float* __restrict__ s, unsigned short* __restrict__ d, int n) {
  int i = (blockIdx.x * 256 + threadIdx.x) * 4;
  if (i >= n) return;
  float4 v = *(const float4*)(s + i);
  ushort4 o;
  o.x = f2bf(v.x); o.y = f2bf(v.y); o.z = f2bf(v.z); o.w = f2bf(v.w);
  *(ushort4*)(d + i) = o;
}

// ---------------- routing: logits -> softmax -> top2, build lists ----------------
__global__ __launch_bounds__(64) void routing_kernel(
    const float* __restrict__ x, const float* __restrict__ gw,
    int* __restrict__ counts, int* __restrict__ list,
    int* __restrict__ slot_of, float* __restrict__ wts) {
  const int n = blockIdx.x;
  const int lane = threadIdx.x;
  const float* xr = x + (size_t)n * CDIM;
  float s[NEXP];
#pragma unroll
  for (int e = 0; e < NEXP; e++) s[e] = 0.f;
  for (int c = lane; c < CDIM; c += 64) {
    float xv = xr[c];
#pragma unroll
    for (int e = 0; e < NEXP; e++) s[e] += xv * gw[e * CDIM + c];
  }
#pragma unroll
  for (int e = 0; e < NEXP; e++) {
    float v = s[e];
    for (int o = 32; o > 0; o >>= 1) v += __shfl_down(v, o);
    s[e] = v;
  }
  if (lane == 0) {
    float mx = s[0];
#pragma unroll
    for (int e = 1; e < NEXP; e++) mx = fmaxf(mx, s[e]);
    float p[NEXP], sum = 0.f;
#pragma unroll
    for (int e = 0; e < NEXP; e++) { p[e] = __expf(s[e] - mx); sum += p[e]; }
    int i0 = 0;
#pragma unroll
    for (int e = 1; e < NEXP; e++) if (p[e] > p[i0]) i0 = e;
    int i1 = (i0 == 0) ? 1 : 0;
#pragma unroll
    for (int e = 0; e < NEXP; e++) if (e != i0 && p[e] > p[i1]) i1 = e;
    float inv = 1.f / sum;
    int s0 = atomicAdd(&counts[i0], 1);
    int s1 = atomicAdd(&counts[i1], 1);
    if (s0 < CAP) list[i0 * CAP + s0] = n; else s0 = 0;
    if (s1 < CAP) list[i1 * CAP + s1] = n; else s1 = 0;
    slot_of[n * 2]     = i0 * CAP + s0;
    slot_of[n * 2 + 1] = i1 * CAP + s1;
    wts[n * 2]     = p[i0] * inv;
    wts[n * 2 + 1] = p[i1] * inv;
  }
}

// ---------------- fused gated GEMM: H = silu(A@B1^T) * (A@B2^T), bf16 out ----------------
// BM=128, BN=64, BK=64, 256 threads (4 waves, 2x2), wave tile 64x32.
template <bool GATHER>
__global__ __launch_bounds__(256) void gemm_gated_kernel(
    const unsigned short* __restrict__ A,
    const unsigned short* __restrict__ B1,
    const unsigned short* __restrict__ B2,
    unsigned short* __restrict__ H,
    int Ka, int ldo,
    const int* __restrict__ list, const int* __restrict__ counts) {
  int cnt = 0;
  if (GATHER) {
    const int e = blockIdx.z;
    cnt = counts[e];
    if (cnt > CAP) cnt = CAP;
    if ((int)blockIdx.y * 128 >= cnt) return;
    B1 += (size_t)e * IDIM * CDIM;
    B2 += (size_t)e * IDIM * CDIM;
    H  += (size_t)e * CAP * IDIM;
    list += e * CAP;
  }
  __shared__ __align__(16) unsigned short As[128 * 64];
  __shared__ __align__(16) unsigned short Bs1[64 * 64];
  __shared__ __align__(16) unsigned short Bs2[64 * 64];

  const int t = threadIdx.x;
  const int wb = t & ~63;

  const unsigned short* aP[4];
#pragma unroll
  for (int j = 0; j < 4; j++) {
    int idx = j * 256 + t;
    int r = idx >> 3, c8 = (idx & 7) * 8;
    int grow;
    if (GATHER) {
      int sr = blockIdx.y * 128 + r;
      grow = (sr < cnt) ? list[sr] : list[0];
    } else {
      grow = blockIdx.y * 128 + r;
    }
    aP[j] = A + (size_t)grow * Ka + c8;
  }
  const unsigned short *bP1[2], *bP2[2];
#pragma unroll
  for (int j = 0; j < 2; j++) {
    int idx = j * 256 + t;
    int r = idx >> 3, c8 = (idx & 7) * 8;
    size_t o = (size_t)(blockIdx.x * 64 + r) * Ka + c8;
    bP1[j] = B1 + o;
    bP2[j] = B2 + o;
  }

  const int lane = t & 63, wid = t >> 6;
  const int wm = wid >> 1, wn = wid & 1;
  const int lrow = lane & 15, lk = (lane >> 4) * 8;
  int aoff[4], boff[2];
#pragma unroll
  for (int m = 0; m < 4; m++) aoff[m] = (wm * 64 + m * 16 + lrow) * 64 + lk;
#pragma unroll
  for (int n = 0; n < 2; n++) boff[n] = (wn * 32 + n * 16 + lrow) * 64 + lk;

  const f32x4 z4 = {0.f, 0.f, 0.f, 0.f};
  f32x4 acc1[4][2], acc2[4][2];
#pragma unroll
  for (int m = 0; m < 4; m++)
#pragma unroll
    for (int n = 0; n < 2; n++) { acc1[m][n] = z4; acc2[m][n] = z4; }

  for (int k0 = 0; k0 < Ka; k0 += 64) {
#pragma unroll
    for (int j = 0; j < 4; j++) GLOAD16(aP[j] + k0, &As[(j * 256 + wb) * 8]);
#pragma unroll
    for (int j = 0; j < 2; j++) {
      GLOAD16(bP1[j] + k0, &Bs1[(j * 256 + wb) * 8]);
      GLOAD16(bP2[j] + k0, &Bs2[(j * 256 + wb) * 8]);
    }
    __syncthreads();
#pragma unroll
    for (int kk = 0; kk < 2; kk++) {
      bf16x8 af[4], b1f[2], b2f[2];
#pragma unroll
      for (int m = 0; m < 4; m++) af[m] = *(const bf16x8*)&As[aoff[m] + kk * 32];
#pragma unroll
      for (int n = 0; n < 2; n++) {
        b1f[n] = *(const bf16x8*)&Bs1[boff[n] + kk * 32];
        b2f[n] = *(const bf16x8*)&Bs2[boff[n] + kk * 32];
      }
#pragma unroll
      for (int m = 0; m < 4; m++)
#pragma unroll
        for (int n = 0; n < 2; n++) {
          acc1[m][n] = __builtin_amdgcn_mfma_f32_16x16x32_bf16(af[m], b1f[n], acc1[m][n], 0, 0, 0);
          acc2[m][n] = __builtin_amdgcn_mfma_f32_16x16x32_bf16(af[m], b2f[n], acc2[m][n], 0, 0, 0);
        }
    }
    __syncthreads();
  }

  const int colb = blockIdx.x * 64 + wn * 32;
  const int rowb = blockIdx.y * 128 + wm * 64;
#pragma unroll
  for (int m = 0; m < 4; m++)
#pragma unroll
    for (int n = 0; n < 2; n++) {
      int col = colb + n * 16 + lrow;
      int row0 = rowb + m * 16 + (lane >> 4) * 4;
#pragma unroll
      for (int r = 0; r < 4; r++) {
        float z = acc1[m][n][r];
        float g = z / (1.f + __expf(-z));   // silu
        H[(size_t)(row0 + r) * ldo + col] = f2bf(g * acc2[m][n][r]);
      }
    }
}

// ---------------- plain B^T GEMM: Out = A@B^T ----------------
// BM=128, BN=128, BK=64, 256 threads (4 waves 2x2), wave tile 64x64.
template <bool EXPERT, bool OUTF32>
__global__ __launch_bounds__(256) void gemm_bt_kernel(
    const unsigned short* __restrict__ A,
    const unsigned short* __restrict__ B,
    void* __restrict__ OutV,
    int Ka, int ldo,
    const int* __restrict__ counts,
    size_t strideA, size_t strideB, size_t strideO) {
  size_t obase = 0;
  if (EXPERT) {
    const int e = blockIdx.z;
    int cnt = counts[e];
    if (cnt > CAP) cnt = CAP;
    if ((int)blockIdx.y * 128 >= cnt) return;
    A += (size_t)e * strideA;
    B += (size_t)e * strideB;
    obase = (size_t)e * strideO;
  }
  __shared__ __align__(16) unsigned short As[128 * 64];
  __shared__ __align__(16) unsigned short Bs[128 * 64];

  const int t = threadIdx.x;
  const int wb = t & ~63;
  const unsigned short *aP[4], *bP[4];
#pragma unroll
  for (int j = 0; j < 4; j++) {
    int idx = j * 256 + t;
    int r = idx >> 3, c8 = (idx & 7) * 8;
    aP[j] = A + (size_t)(blockIdx.y * 128 + r) * Ka + c8;
    bP[j] = B + (size_t)(blockIdx.x * 128 + r) * Ka + c8;
  }
  const int lane = t & 63, wid = t >> 6;
  const int wm = wid >> 1, wn = wid & 1;
  const int lrow = lane & 15, lk = (lane >> 4) * 8;
  int aoff[4], boff[4];
#pragma unroll
  for (int m = 0; m < 4; m++) aoff[m] = (wm * 64 + m * 16 + lrow) * 64 + lk;
#pragma unroll
  for (int n = 0; n < 4; n++) boff[n] = (wn * 64 + n * 16 + lrow) * 64 + lk;

  const f32x4 z4 = {0.f, 0.f, 0.f, 0.f};
  f32x4 acc[4][4];
#pragma unroll
  for (int m = 0; m < 4; m++)
#pragma unroll
    for (int n = 0; n < 4; n++) acc[m][n] = z4;

  for (int k0 = 0; k0 < Ka; k0 += 64) {
#pragma unroll
    for (int j = 0; j < 4; j++) {
      GLOAD16(aP[j] + k0, &As[(j * 256 + wb) * 8]);
      GLOAD16(bP[j] + k0, &Bs[(j * 256 + wb) * 8]);
    }
    __syncthreads();
#pragma unroll
    for (int kk = 0; kk < 2; kk++) {
      bf16x8 af[4], bfv[4];
#pragma unroll
      for (int m = 0; m < 4; m++) af[m] = *(const bf16x8*)&As[aoff[m] + kk * 32];
#pragma unroll
      for (int n = 0; n < 4; n++) bfv[n] = *(const bf16x8*)&Bs[boff[n] + kk * 32];
#pragma unroll
      for (int m = 0; m < 4; m++)
#pragma unroll
        for (int n = 0; n < 4; n++)
          acc[m][n] = __builtin_amdgcn_mfma_f32_16x16x32_bf16(af[m], bfv[n], acc[m][n], 0, 0, 0);
    }
    __syncthreads();
  }

  const int colb = blockIdx.x * 128 + wn * 64;
  const int rowb = blockIdx.y * 128 + wm * 64;
#pragma unroll
  for (int m = 0; m < 4; m++)
#pragma unroll
    for (int n = 0; n < 4; n++) {
      int col = colb + n * 16 + lrow;
      int row0 = rowb + m * 16 + (lane >> 4) * 4;
#pragma unroll
      for (int r = 0; r < 4; r++) {
        if (OUTF32)
          ((float*)OutV)[obase + (size_t)(row0 + r) * ldo + col] = acc[m][n][r];
        else
          ((unsigned short*)OutV)[obase + (size_t)(row0 + r) * ldo + col] = f2bf(acc[m][n][r]);
      }
    }
}

// ---------------- weighted expert combine into y ----------------
__global__ __launch_bounds__(256) void combine_kernel(
    float* __restrict__ y, const unsigned short* __restrict__ eo,
    const int* __restrict__ slot_of, const float* __restrict__ wts) {
  int idx = blockIdx.x * 256 + threadIdx.x;
  int n = idx >> 9;            // C/4 = 512 chunks per token
  int c = (idx & 511) * 4;
  float* yp = y + (size_t)n * CDIM + c;
  float4 v = *(float4*)yp;
#pragma unroll
  for (int k = 0; k < 2; k++) {
    int slot = slot_of[n * 2 + k];
    float w = wts[n * 2 + k];
    ushort4 h = *(const ushort4*)(eo + (size_t)slot * CDIM + c);
    v.x += w * bf2f(h.x);
    v.y += w * bf2f(h.y);
    v.z += w * bf2f(h.z);
    v.w += w * bf2f(h.w);
  }
  *(float4*)yp = v;
}

extern "C" void kernel_launch(void* const* d_in, const int* in_sizes, int n_in,
                              void* d_out, int out_size, void* d_ws, size_t ws_size,
                              hipStream_t stream) {
  const float* x   = (const float*)d_in[0];
  const float* gw  = (const float*)d_in[1];
  const float* w1  = (const float*)d_in[2];
  const float* w2  = (const float*)d_in[3];
  const float* w3  = (const float*)d_in[4];
  const float* sw1 = (const float*)d_in[5];
  const float* sw2 = (const float*)d_in[6];
  const float* sw3 = (const float*)d_in[7];
  float* y = (float*)d_out;

  char* ws = (char*)d_ws;
  size_t off = 0;
  auto alloc = [&](size_t b) -> void* {
    void* p = ws + off;
    off += (b + 255) & ~(size_t)255;
    return p;
  };
  unsigned short* xb   = (unsigned short*)alloc((size_t)N_TOK * CDIM * 2);
  unsigned short* w1b  = (unsigned short*)alloc((size_t)NEXP * IDIM * CDIM * 2);
  unsigned short* w2b  = (unsigned short*)alloc((size_t)NEXP * IDIM * CDIM * 2);
  unsigned short* w3b  = (unsigned short*)alloc((size_t)NEXP * CDIM * IDIM * 2);
  unsigned short* sw1b = (unsigned short*)alloc((size_t)ISDIM * CDIM * 2);
  unsigned short* sw2b = (unsigned short*)alloc((size_t)ISDIM * CDIM * 2);
  unsigned short* sw3b = (unsigned short*)alloc((size_t)CDIM * ISDIM * 2);
  unsigned short* hs   = (unsigned short*)alloc((size_t)N_TOK * ISDIM * 2);
  unsigned short* he   = (unsigned short*)alloc((size_t)NEXP * CAP * IDIM * 2);
  unsigned short* eo   = (unsigned short*)alloc((size_t)NEXP * CAP * CDIM * 2);
  int*   counts  = (int*)alloc(NEXP * 4);
  int*   list    = (int*)alloc((size_t)NEXP * CAP * 4);
  int*   slot_of = (int*)alloc((size_t)N_TOK * 2 * 4);
  float* wtsb    = (float*)alloc((size_t)N_TOK * 2 * 4);

  hipMemsetAsync(counts, 0, NEXP * 4, stream);
  routing_kernel<<<N_TOK, 64, 0, stream>>>(x, gw, counts, list, slot_of, wtsb);

  auto cvt = [&](const float* s, unsigned short* d, size_t n) {
    cvt_kernel<<<(int)(n / 1024), 256, 0, stream>>>(s, d, (int)n);
  };
  cvt(x,   xb,   (size_t)N_TOK * CDIM);
  cvt(w1,  w1b,  (size_t)NEXP * IDIM * CDIM);
  cvt(w2,  w2b,  (size_t)NEXP * IDIM * CDIM);
  cvt(w3,  w3b,  (size_t)NEXP * CDIM * IDIM);
  cvt(sw1, sw1b, (size_t)ISDIM * CDIM);
  cvt(sw2, sw2b, (size_t)ISDIM * CDIM);
  cvt(sw3, sw3b, (size_t)CDIM * ISDIM);

  // shared expert gated MLP: hs = silu(x@sw1^T)*(x@sw2^T)   [4096 x 2816]
  gemm_gated_kernel<false><<<dim3(ISDIM / 64, N_TOK / 128, 1), 256, 0, stream>>>(
      xb, sw1b, sw2b, hs, CDIM, ISDIM, nullptr, nullptr);
  // expert gated MLP (gathered): he = silu(xg@w1^T)*(xg@w2^T) [8 x CAP x 1408]
  gemm_gated_kernel<true><<<dim3(IDIM / 64, CAP / 128, NEXP), 256, 0, stream>>>(
      xb, w1b, w2b, he, CDIM, IDIM, list, counts);
  // shared proj: y = hs@sw3^T (fp32, direct to output)
  gemm_bt_kernel<false, true><<<dim3(CDIM / 128, N_TOK / 128, 1), 256, 0, stream>>>(
      hs, sw3b, y, ISDIM, CDIM, nullptr, 0, 0, 0);
  // expert proj: eo = he@w3^T (bf16)
  gemm_bt_kernel<true, false><<<dim3(CDIM / 128, CAP / 128, NEXP), 256, 0, stream>>>(
      he, w3b, eo, IDIM, CDIM, counts,
      (size_t)CAP * IDIM, (size_t)CDIM * IDIM, (size_t)CAP * CDIM);
  // y += sum_k w_k * eo[slot_k]
  combine_kernel<<<(N_TOK * (CDIM / 4)) / 256, 256, 0, stream>>>(y, eo, slot_of, wtsb);
}